// Round 6
// baseline (280.748 us; speedup 1.0000x reference)
//
#include <hip/hip_runtime.h>
#include <stdint.h>

#define B 8
#define N 200000
#define C 80
#define K 2000
#define HBUCK 4096
#define CAND_CAP 2048
#define BOUND_CAP 2048
#define ENT_M 4096              // CAND_CAP + BOUND_CAP
#define RANK_BLKS 16            // ENT_M / 256
#define BLK 256
#define SBLK 512                // k_score block size
#define ROWS_PB (SBLK / 4)      // 128 rows per k_score block (4 lanes per row)
#define SBPB ((N + ROWS_PB - 1) / ROWS_PB)            // 1563 blocks per batch
#define BPB4 ((N + 1023) / 1024)                      // 196 blocks per batch (uint4)

// Bucket mapping: scores are float bits in (0, 1.0); off = 0x3F800000 - bits >= 1.
// bucket = min(4095, (off-1)>>8): buckets 0..4094 are 256-ulp slices of (0.9375, 1),
// bucket 4095 holds everything below. Descending score == ascending bucket.
__device__ __forceinline__ uint32_t key_bucket(uint32_t key) {
    uint32_t off = 0x3F800000u - key;
    uint32_t b = (off - 1u) >> 8;
    return b > 4095u ? 4095u : b;
}

// ---------------- kernel 0: init outputs(-1), hist(0), state(0) ----------
__global__ void k_init(float* out, uint32_t* hist, uint32_t* state) {
    int i = blockIdx.x * blockDim.x + threadIdx.x;
    if (i < B * K * 8) out[i] = -1.0f;
    if (i < B * HBUCK) hist[i] = 0;
    if (i < B * 8) state[i] = 0;
}

// ---------------- kernel 1: score + argmax + hist (streaming, no LDS) ----
// Each row of 80 floats is owned by a 4-lane group; lane q loads float4s
// {q, q+4, q+8, q+12, q+16}: each wave instruction = 16 x 64B fully-consumed
// segments. No LDS staging, no barrier between loads and use -> continuous
// load issue at 32 waves/CU (LDS = 16KB hist only).
__global__ __launch_bounds__(SBLK) void k_score(const float* __restrict__ cls,
                                                uint32_t* __restrict__ keys,
                                                uint8_t* __restrict__ labels,
                                                uint32_t* __restrict__ hist) {
    __shared__ uint32_t h[HBUCK];                           // 16 KB
    for (int t = threadIdx.x; t < HBUCK; t += SBLK) h[t] = 0;
    __syncthreads();

    int b = blockIdx.x / SBPB;
    int r = (blockIdx.x % SBPB) * ROWS_PB + (threadIdx.x >> 2);
    int q = threadIdx.x & 3;
    bool active = (r < N);

    float maxv = -1.0f;
    uint32_t cl = 0;
    if (active) {
        const float4* rowp = (const float4*)(cls + ((size_t)b * N + r) * C);
        float4 v[5];
        #pragma unroll
        for (int j = 0; j < 5; ++j) v[j] = rowp[q + 4 * j];
        #pragma unroll
        for (int j = 0; j < 5; ++j) {
            uint32_t cbase = (uint32_t)(q + 4 * j) * 4;   // ascending in j
            if (v[j].x > maxv) { maxv = v[j].x; cl = cbase; }
            if (v[j].y > maxv) { maxv = v[j].y; cl = cbase + 1; }
            if (v[j].z > maxv) { maxv = v[j].z; cl = cbase + 2; }
            if (v[j].w > maxv) { maxv = v[j].w; cl = cbase + 3; }
        }
    }
    // combine (max, class) across the 4-lane group; tie -> lower class
    // (== first occurrence, matching jnp.argmax).
    #pragma unroll
    for (int m = 1; m <= 2; m <<= 1) {
        float ov = __shfl_xor(maxv, m, 64);
        uint32_t oc = __shfl_xor(cl, m, 64);
        if (ov > maxv || (ov == maxv && oc < cl)) { maxv = ov; cl = oc; }
    }
    if (active && q == 0) {
        uint32_t key = (maxv > 0.05f) ? __float_as_uint(maxv) : 0u;
        keys[(size_t)b * N + r] = key;
        labels[(size_t)b * N + r] = (uint8_t)cl;
        if (key) atomicAdd(&h[key_bucket(key)], 1u);
    }
    __syncthreads();
    for (int t = threadIdx.x; t < HBUCK; t += SBLK) {
        uint32_t c = h[t];
        if (c) atomicAdd(&hist[b * HBUCK + t], c);
    }
}

// ---------------- kernel 2: per-batch prefix scan -> cutoff bucket -------
__global__ __launch_bounds__(256) void k_scan(const uint32_t* __restrict__ hist,
                                              uint32_t* __restrict__ state) {
    int b = blockIdx.x;
    const uint32_t* h = hist + b * HBUCK;
    __shared__ uint32_t p[256];
    __shared__ uint32_t sd;
    int t = threadIdx.x;
    if (t == 0) sd = 4096u;   // take-all sentinel (total < K)
    uint32_t loc[16];
    uint32_t s = 0;
    #pragma unroll
    for (int j = 0; j < 16; ++j) { loc[j] = h[t * 16 + j]; s += loc[j]; }
    p[t] = s;
    __syncthreads();
    // inclusive prefix scan over 256 chunk sums (Hillis-Steele)
    for (int off = 1; off < 256; off <<= 1) {
        uint32_t add = (t >= off) ? p[t - off] : 0;
        __syncthreads();
        p[t] += add;
        __syncthreads();
    }
    uint32_t total = p[255];
    if (total >= K) {
        uint32_t run = p[t] - s;   // count in buckets before this chunk
        #pragma unroll
        for (int j = 0; j < 16; ++j) {
            uint32_t c = loc[j];
            if (run < K && run + c >= K) sd = (uint32_t)(t * 16 + j); // unique writer
            run += c;
        }
    }
    __syncthreads();
    if (t == 0) state[b * 8 + 2] = sd;
}

// ---------------- kernel 3: collect candidates + boundary (uint4) --------
__global__ __launch_bounds__(BLK) void k_collect(const uint32_t* __restrict__ keys,
                                                 uint32_t* __restrict__ state,
                                                 uint64_t* __restrict__ cand,
                                                 uint64_t* __restrict__ bound) {
    int b = blockIdx.x / BPB4;
    int base = (blockIdx.x % BPB4) * 1024 + threadIdx.x * 4;
    uint32_t d = state[b * 8 + 2];
    uint4 kv = make_uint4(0, 0, 0, 0);
    if (base < N) kv = *(const uint4*)(keys + (size_t)b * N + base);  // N%4==0
    uint32_t ks[4] = { kv.x, kv.y, kv.z, kv.w };
    int lane = threadIdx.x & 63;

    #pragma unroll
    for (int e = 0; e < 4; ++e) {
        uint32_t key = ks[e];
        uint32_t bkt = key_bucket(key);
        bool isCand  = key && (bkt < d);
        bool isBound = key && (bkt == d);
        uint32_t i = (uint32_t)(base + e);
        uint64_t entry = ((uint64_t)key << 32) | (uint32_t)(~i);

        unsigned long long mc = __ballot(isCand);
        if (mc) {
            int leader = __ffsll((long long)mc) - 1;
            uint32_t basev = 0;
            if (lane == leader) basev = atomicAdd(&state[b * 8 + 4], (uint32_t)__popcll(mc));
            basev = __shfl(basev, leader);
            uint32_t pos = basev + (uint32_t)__popcll(mc & ((1ull << lane) - 1ull));
            if (isCand && pos < CAND_CAP) cand[(size_t)b * CAND_CAP + pos] = entry;
        }
        unsigned long long mb = __ballot(isBound);
        if (mb) {
            int leader = __ffsll((long long)mb) - 1;
            uint32_t basev = 0;
            if (lane == leader) basev = atomicAdd(&state[b * 8 + 5], (uint32_t)__popcll(mb));
            basev = __shfl(basev, leader);
            uint32_t pos = basev + (uint32_t)__popcll(mb & ((1ull << lane) - 1ull));
            if (isBound && pos < BOUND_CAP) bound[(size_t)b * BOUND_CAP + pos] = entry;
        }
    }
}

// ---------------- kernel 4: rank-by-counting + scatter outputs ----------
__global__ __launch_bounds__(256) void k_rank(const uint64_t* __restrict__ cand,
                                              const uint64_t* __restrict__ bound,
                                              const uint32_t* __restrict__ state,
                                              const uint8_t* __restrict__ labels,
                                              const float* __restrict__ boxes,
                                              float* __restrict__ out) {
    __shared__ uint64_t a[ENT_M];       // 32 KB
    int b = blockIdx.x / RANK_BLKS;
    int t0 = (blockIdx.x % RANK_BLKS) * 256;
    uint32_t cc = state[b * 8 + 4]; if (cc > CAND_CAP) cc = CAND_CAP;
    uint32_t bc = state[b * 8 + 5]; if (bc > BOUND_CAP) bc = BOUND_CAP;
    for (int i = threadIdx.x; i < ENT_M; i += 256) {
        uint64_t v = 0;
        if (i < (int)cc) v = cand[(size_t)b * CAND_CAP + i];
        else if (i < (int)(cc + bc)) v = bound[(size_t)b * BOUND_CAP + (i - cc)];
        a[i] = v;
    }
    __syncthreads();
    uint64_t e = a[t0 + threadIdx.x];
    if (e == 0) return;                  // padding / empty slot
    uint32_t rank = 0;
    #pragma unroll 8
    for (int j = 0; j < ENT_M; ++j) rank += (a[j] > e) ? 1u : 0u;  // LDS broadcast
    if (rank >= K) return;

    uint32_t sb  = (uint32_t)(e >> 32);
    uint32_t idx = ~((uint32_t)e);
    float* out_boxes  = out;                           // [B,K,6]
    float* out_scores = out + (size_t)B * K * 6;       // [B,K]
    float* out_labels = out_scores + (size_t)B * K;    // [B,K]
    out_scores[(size_t)b * K + rank] = __uint_as_float(sb);
    out_labels[(size_t)b * K + rank] = (float)labels[(size_t)b * N + idx];
    const float* bx = boxes + ((size_t)b * N + idx) * 6;
    float* ob = out_boxes + ((size_t)b * K + rank) * 6;
    #pragma unroll
    for (int c2 = 0; c2 < 6; ++c2) ob[c2] = bx[c2];
}

extern "C" void kernel_launch(void* const* d_in, const int* in_sizes, int n_in,
                              void* d_out, int out_size, void* d_ws, size_t ws_size,
                              hipStream_t stream) {
    const float* boxes = (const float*)d_in[0];          // [B,N,6]
    const float* cls   = (const float*)d_in[1];          // [B,N,C]
    float* out = (float*)d_out;

    char* ws = (char*)d_ws;
    uint32_t* keys   = (uint32_t*)ws;                              // B*N u32
    uint8_t*  labels = (uint8_t*)(ws + (size_t)B * N * 4);         // B*N u8
    uint32_t* hist   = (uint32_t*)(ws + (size_t)B * N * 5);        // B*4096 u32
    uint32_t* state  = hist + (size_t)B * HBUCK;                   // B*8 u32
    uint64_t* cand   = (uint64_t*)(state + B * 8);
    uint64_t* bound  = cand + (size_t)B * CAND_CAP;

    int init_total = B * K * 8;   // 128000 >= B*HBUCK and B*8
    k_init<<<(init_total + 255) / 256, 256, 0, stream>>>(out, hist, state);
    k_score<<<B * SBPB, SBLK, 0, stream>>>(cls, keys, labels, hist);
    k_scan<<<B, 256, 0, stream>>>(hist, state);
    k_collect<<<B * BPB4, BLK, 0, stream>>>(keys, state, cand, bound);
    k_rank<<<B * RANK_BLKS, 256, 0, stream>>>(cand, bound, state, labels, boxes, out);
}

// Round 7
// 247.503 us; speedup vs baseline: 1.1343x; 1.1343x over previous
//
#include <hip/hip_runtime.h>
#include <stdint.h>

#define B 8
#define N 200000
#define C 80
#define K 2000
#define HBUCK 4096
#define CAND_CAP 2048
#define BOUND_CAP 2048
#define ENT_M 4096              // CAND_CAP + BOUND_CAP
#define RANK_BLKS 16            // ENT_M / 256
#define BLK 256
#define SEG_PER_B 96            // hist segments (blocks) per batch
#define NSEG (B * SEG_PER_B)    // 768 k_score blocks = 3/CU exactly
#define CHUNK_ROWS 256
#define NCHUNK ((N + CHUNK_ROWS - 1) / CHUNK_ROWS)    // 782 chunks per batch
#define F4_PER_ROW (C / 4)                            // 20
#define ROW_STRIDE 21                                 // coprime 32 -> conflict-free
#define F4_PER_THREAD (CHUNK_ROWS * F4_PER_ROW / BLK) // 20
#define BPB4 ((N + 1023) / 1024)                      // 196 blocks per batch (uint4)

// Bucket mapping: scores are float bits in (0, 1.0); off = 0x3F800000 - bits >= 1.
// bucket = min(4095, (off-1)>>8): buckets 0..4094 are 256-ulp slices of (0.9375, 1),
// bucket 4095 holds everything below. Descending score == ascending bucket.
__device__ __forceinline__ uint32_t key_bucket(uint32_t key) {
    uint32_t off = 0x3F800000u - key;
    uint32_t b = (off - 1u) >> 8;
    return b > 4095u ? 4095u : b;
}

// ---------------- kernel 0: init outputs(-1), state(0) ----------------
__global__ void k_init(float* out, uint32_t* state) {
    int i = blockIdx.x * blockDim.x + threadIdx.x;
    if (i < B * K * 8) out[i] = -1.0f;
    if (i < B * 8) state[i] = 0;
}

// ---------------- kernel 1: score + argmax + per-segment hist ----------
// 768 grid-strided blocks (96 per batch), each accumulates its LDS hist over
// ~8 chunks of 256 rows, then flushes ONCE with plain coalesced stores into a
// private seghist segment. Zero global atomics.
__global__ __launch_bounds__(BLK) void k_score(const float* __restrict__ cls,
                                               uint32_t* __restrict__ keys,
                                               uint8_t* __restrict__ labels,
                                               uint32_t* __restrict__ seghist) {
    __shared__ uint32_t h[HBUCK];                           // 16 KB
    __shared__ float    sval[CHUNK_ROWS * ROW_STRIDE];      // 21 KB
    __shared__ uint16_t sidx[CHUNK_ROWS * ROW_STRIDE];      // 10.5 KB
    for (int t = threadIdx.x; t < HBUCK; t += BLK) h[t] = 0;

    int b = blockIdx.x / SEG_PER_B;
    int s = blockIdx.x % SEG_PER_B;
    const float* clsb = cls + (size_t)b * N * C;

    for (int c = s; c < NCHUNK; c += SEG_PER_B) {
        int row0 = c * CHUNK_ROWS;
        const float4* src = (const float4*)(clsb + (size_t)row0 * C);

        if (row0 + CHUNK_ROWS <= N) {
            // fast path: register-batched loads, contiguous 1KB per wave-instr
            float4 v[F4_PER_THREAD];
            #pragma unroll
            for (int kk = 0; kk < F4_PER_THREAD; ++kk)
                v[kk] = src[threadIdx.x + kk * BLK];
            #pragma unroll
            for (int kk = 0; kk < F4_PER_THREAD; ++kk) {
                int f = threadIdx.x + kk * BLK;
                int r = f / F4_PER_ROW;
                int cc = f % F4_PER_ROW;
                float m4 = v[kk].x; uint32_t a4 = 0;
                if (v[kk].y > m4) { m4 = v[kk].y; a4 = 1; }
                if (v[kk].z > m4) { m4 = v[kk].z; a4 = 2; }
                if (v[kk].w > m4) { m4 = v[kk].w; a4 = 3; }
                sval[r * ROW_STRIDE + cc] = m4;
                sidx[r * ROW_STRIDE + cc] = (uint16_t)(cc * 4 + a4);
            }
        } else {
            // tail chunk (one per batch): guarded
            #pragma unroll
            for (int kk = 0; kk < F4_PER_THREAD; ++kk) {
                int f = threadIdx.x + kk * BLK;
                int r = f / F4_PER_ROW;
                int cc = f % F4_PER_ROW;
                float m4 = -1.0f; uint32_t a4 = 0;
                if (row0 + r < N) {
                    float4 v = src[f];
                    m4 = v.x; a4 = 0;
                    if (v.y > m4) { m4 = v.y; a4 = 1; }
                    if (v.z > m4) { m4 = v.z; a4 = 2; }
                    if (v.w > m4) { m4 = v.w; a4 = 3; }
                }
                sval[r * ROW_STRIDE + cc] = m4;
                sidx[r * ROW_STRIDE + cc] = (uint16_t)(cc * 4 + a4);
            }
        }
        __syncthreads();

        int grow = row0 + threadIdx.x;
        if (grow < N) {
            int base = threadIdx.x * ROW_STRIDE;
            float maxv = -1.0f; uint32_t maxi = 0;
            #pragma unroll
            for (int cc = 0; cc < F4_PER_ROW; ++cc) {
                float v = sval[base + cc];
                if (v > maxv) { maxv = v; maxi = sidx[base + cc]; }
            }
            uint32_t key = (maxv > 0.05f) ? __float_as_uint(maxv) : 0u;
            keys[(size_t)b * N + grow] = key;
            labels[(size_t)b * N + grow] = (uint8_t)maxi;
            if (key) atomicAdd(&h[key_bucket(key)], 1u);
        }
        __syncthreads();   // protect sval/sidx (and h) before next chunk
    }

    // single flush: plain coalesced stores, no atomics
    uint32_t* seg = seghist + (size_t)blockIdx.x * HBUCK;
    for (int t = threadIdx.x; t < HBUCK; t += BLK) seg[t] = h[t];
}

// ---------------- kernel 1b: reduce segment hists -> per-batch hist ------
__global__ __launch_bounds__(256) void k_reduce(const uint32_t* __restrict__ seghist,
                                                uint32_t* __restrict__ hist) {
    int gb = blockIdx.x * 256 + threadIdx.x;   // grid = B*HBUCK/256 = 128 blocks
    int b = gb / HBUCK;
    int bucket = gb - b * HBUCK;
    const uint32_t* base = seghist + ((size_t)b * SEG_PER_B) * HBUCK + bucket;
    uint32_t s = 0;
    #pragma unroll 8
    for (int j = 0; j < SEG_PER_B; ++j) s += base[(size_t)j * HBUCK];
    hist[gb] = s;
}

// ---------------- kernel 2: per-batch prefix scan -> cutoff bucket -------
__global__ __launch_bounds__(256) void k_scan(const uint32_t* __restrict__ hist,
                                              uint32_t* __restrict__ state) {
    int b = blockIdx.x;
    const uint32_t* h = hist + b * HBUCK;
    __shared__ uint32_t p[256];
    __shared__ uint32_t sd;
    int t = threadIdx.x;
    if (t == 0) sd = 4096u;   // take-all sentinel (total < K)
    uint32_t loc[16];
    uint32_t s = 0;
    #pragma unroll
    for (int j = 0; j < 16; ++j) { loc[j] = h[t * 16 + j]; s += loc[j]; }
    p[t] = s;
    __syncthreads();
    // inclusive prefix scan over 256 chunk sums (Hillis-Steele)
    for (int off = 1; off < 256; off <<= 1) {
        uint32_t add = (t >= off) ? p[t - off] : 0;
        __syncthreads();
        p[t] += add;
        __syncthreads();
    }
    uint32_t total = p[255];
    if (total >= K) {
        uint32_t run = p[t] - s;   // count in buckets before this chunk
        #pragma unroll
        for (int j = 0; j < 16; ++j) {
            uint32_t c = loc[j];
            if (run < K && run + c >= K) sd = (uint32_t)(t * 16 + j); // unique writer
            run += c;
        }
    }
    __syncthreads();
    if (t == 0) state[b * 8 + 2] = sd;
}

// ---------------- kernel 3: collect candidates + boundary (uint4) --------
__global__ __launch_bounds__(BLK) void k_collect(const uint32_t* __restrict__ keys,
                                                 uint32_t* __restrict__ state,
                                                 uint64_t* __restrict__ cand,
                                                 uint64_t* __restrict__ bound) {
    int b = blockIdx.x / BPB4;
    int base = (blockIdx.x % BPB4) * 1024 + threadIdx.x * 4;
    uint32_t d = state[b * 8 + 2];
    uint4 kv = make_uint4(0, 0, 0, 0);
    if (base < N) kv = *(const uint4*)(keys + (size_t)b * N + base);  // N%4==0
    uint32_t ks[4] = { kv.x, kv.y, kv.z, kv.w };
    int lane = threadIdx.x & 63;

    #pragma unroll
    for (int e = 0; e < 4; ++e) {
        uint32_t key = ks[e];
        uint32_t bkt = key_bucket(key);
        bool isCand  = key && (bkt < d);
        bool isBound = key && (bkt == d);
        uint32_t i = (uint32_t)(base + e);
        uint64_t entry = ((uint64_t)key << 32) | (uint32_t)(~i);

        unsigned long long mc = __ballot(isCand);
        if (mc) {
            int leader = __ffsll((long long)mc) - 1;
            uint32_t basev = 0;
            if (lane == leader) basev = atomicAdd(&state[b * 8 + 4], (uint32_t)__popcll(mc));
            basev = __shfl(basev, leader);
            uint32_t pos = basev + (uint32_t)__popcll(mc & ((1ull << lane) - 1ull));
            if (isCand && pos < CAND_CAP) cand[(size_t)b * CAND_CAP + pos] = entry;
        }
        unsigned long long mb = __ballot(isBound);
        if (mb) {
            int leader = __ffsll((long long)mb) - 1;
            uint32_t basev = 0;
            if (lane == leader) basev = atomicAdd(&state[b * 8 + 5], (uint32_t)__popcll(mb));
            basev = __shfl(basev, leader);
            uint32_t pos = basev + (uint32_t)__popcll(mb & ((1ull << lane) - 1ull));
            if (isBound && pos < BOUND_CAP) bound[(size_t)b * BOUND_CAP + pos] = entry;
        }
    }
}

// ---------------- kernel 4: rank-by-counting + scatter outputs ----------
__global__ __launch_bounds__(256) void k_rank(const uint64_t* __restrict__ cand,
                                              const uint64_t* __restrict__ bound,
                                              const uint32_t* __restrict__ state,
                                              const uint8_t* __restrict__ labels,
                                              const float* __restrict__ boxes,
                                              float* __restrict__ out) {
    __shared__ uint64_t a[ENT_M];       // 32 KB
    int b = blockIdx.x / RANK_BLKS;
    int t0 = (blockIdx.x % RANK_BLKS) * 256;
    uint32_t cc = state[b * 8 + 4]; if (cc > CAND_CAP) cc = CAND_CAP;
    uint32_t bc = state[b * 8 + 5]; if (bc > BOUND_CAP) bc = BOUND_CAP;
    for (int i = threadIdx.x; i < ENT_M; i += 256) {
        uint64_t v = 0;
        if (i < (int)cc) v = cand[(size_t)b * CAND_CAP + i];
        else if (i < (int)(cc + bc)) v = bound[(size_t)b * BOUND_CAP + (i - cc)];
        a[i] = v;
    }
    __syncthreads();
    uint64_t e = a[t0 + threadIdx.x];
    if (e == 0) return;                  // padding / empty slot
    uint32_t rank = 0;
    #pragma unroll 8
    for (int j = 0; j < ENT_M; ++j) rank += (a[j] > e) ? 1u : 0u;  // LDS broadcast
    if (rank >= K) return;

    uint32_t sb  = (uint32_t)(e >> 32);
    uint32_t idx = ~((uint32_t)e);
    float* out_boxes  = out;                           // [B,K,6]
    float* out_scores = out + (size_t)B * K * 6;       // [B,K]
    float* out_labels = out_scores + (size_t)B * K;    // [B,K]
    out_scores[(size_t)b * K + rank] = __uint_as_float(sb);
    out_labels[(size_t)b * K + rank] = (float)labels[(size_t)b * N + idx];
    const float* bx = boxes + ((size_t)b * N + idx) * 6;
    float* ob = out_boxes + ((size_t)b * K + rank) * 6;
    #pragma unroll
    for (int c2 = 0; c2 < 6; ++c2) ob[c2] = bx[c2];
}

extern "C" void kernel_launch(void* const* d_in, const int* in_sizes, int n_in,
                              void* d_out, int out_size, void* d_ws, size_t ws_size,
                              hipStream_t stream) {
    const float* boxes = (const float*)d_in[0];          // [B,N,6]
    const float* cls   = (const float*)d_in[1];          // [B,N,C]
    float* out = (float*)d_out;

    char* ws = (char*)d_ws;
    uint32_t* keys    = (uint32_t*)ws;                             // B*N u32 (6.4 MB)
    uint8_t*  labels  = (uint8_t*)(ws + (size_t)B * N * 4);        // B*N u8  (1.6 MB)
    uint32_t* hist    = (uint32_t*)(ws + (size_t)B * N * 5);       // B*4096 u32
    uint32_t* state   = hist + (size_t)B * HBUCK;                  // B*8 u32
    uint64_t* cand    = (uint64_t*)(state + B * 8);                // 8-aligned
    uint64_t* bound   = cand + (size_t)B * CAND_CAP;
    uint32_t* seghist = (uint32_t*)(bound + (size_t)B * BOUND_CAP); // 768*4096 u32 (12.6 MB)

    k_init<<<(B * K * 8 + 255) / 256, 256, 0, stream>>>(out, state);
    k_score<<<NSEG, BLK, 0, stream>>>(cls, keys, labels, seghist);
    k_reduce<<<B * HBUCK / 256, 256, 0, stream>>>(seghist, hist);
    k_scan<<<B, 256, 0, stream>>>(hist, state);
    k_collect<<<B * BPB4, BLK, 0, stream>>>(keys, state, cand, bound);
    k_rank<<<B * RANK_BLKS, 256, 0, stream>>>(cand, bound, state, labels, boxes, out);
}